// Round 19
// baseline (157.907 us; speedup 1.0000x reference)
//
#include <hip/hip_runtime.h>
#include <hip/hip_bf16.h>
#include <cmath>

#define N 512
#define C_S 384
#define C_Z 128
#define C_H 16
#define H 12
#define PQ 4
#define PV 8

#define NJC 4            // j-split chunks in k_av
#define JCHUNK (N / NJC) // 128
#define NPART 2016       // per (i,jc) partial vector: o(192) + o_pt(288) + o_pair(1536)
#define NFEAT 2112       // o(192) + o_pair(1536) + ptsf(288) + pnorm(96)
#define NRAW 1152        // q(192) + kv(384) + qp(144) + kvp(432)
#define KSPLIT 11        // k-chunks in k_final_part (2112 = 11*192)
#define KCHUNK 192
#define PSPLIT 3         // split-K in k_gemm_proj (384 = 3*128)

// workspace layout (floats)
#define WS_Q    0
#define WS_K    (WS_Q + N*H*C_H)
#define WS_SM   WS_K                          // 512*192 floats (tile softmax stats)
#define WS_V    (WS_K + N*H*C_H)
#define WS_QP   (WS_V + N*H*C_H)
#define WS_KP   (WS_QP + N*H*PQ*3)
#define WS_VP   (WS_KP + N*H*PQ*3)
#define WS_PART (WS_VP + N*H*PV*3)            // 512*4*2016 floats
#define WS_FEAT (WS_PART + N*NJC*NPART)       // 512*2112 floats
#define WS_RAW  WS_PART                       // raw partials [3][512][1152]; consumed by k_post
#define WS_KT   (WS_PART + 2000000)           // kT4[48][512][4]; live k_post -> k_logits
#define WS_KPT  (WS_KT + 98304)               // kpT4[36][512][4]; live k_post -> k_logits
#define WS_WBT  (WS_KPT + 73728)              // wbT[12][128]; live k_post -> k_logits
#define WS_FOUT WS_PART                       // fout[11][512][384]; dead after k_feat

// ---------------------------------------------------------------------------
// Kernel 1a: raw projections, split-K GEMM. Grid (8, 18, 3).
// ---------------------------------------------------------------------------
__global__ __launch_bounds__(256) void k_gemm_proj(
    const float* __restrict__ s,
    const float* __restrict__ Wq,  const float* __restrict__ bq,
    const float* __restrict__ Wkv, const float* __restrict__ bkv,
    const float* __restrict__ Wqp, const float* __restrict__ bqp,
    const float* __restrict__ Wkvp,const float* __restrict__ bkvp,
    float* __restrict__ raw_out)
{
    const int m0 = blockIdx.x * 64;
    const int c0 = blockIdx.y * 64;
    const int kc = blockIdx.z;
    const int t  = threadIdx.x;
    const int tc = t & 15;
    const int tm = t >> 4;

    __shared__ float st[64 * 33];
    __shared__ float wt[32 * 64];

    float acc[4][4];
    if (kc == 0) {
#pragma unroll
        for (int u = 0; u < 4; ++u) {
            int col = c0 + tc*4 + u;
            const float* b; int cb;
            if (col < 192)      { b = bq;   cb = 0; }
            else if (col < 576) { b = bkv;  cb = 192; }
            else if (col < 720) { b = bqp;  cb = 576; }
            else                { b = bkvp; cb = 720; }
            float bv = b[col - cb];
#pragma unroll
            for (int r = 0; r < 4; ++r) acc[r][u] = bv;
        }
    } else {
#pragma unroll
        for (int u = 0; u < 4; ++u)
#pragma unroll
            for (int r = 0; r < 4; ++r) acc[r][u] = 0.0f;
    }

    const int kbase = kc * 128;
    for (int k0 = kbase; k0 < kbase + 128; k0 += 32) {
        __syncthreads();
        for (int e = t; e < 512; e += 256) {
            int row = e >> 3, kq = e & 7;
            float4 v = *(const float4*)&s[(size_t)(m0 + row)*C_S + k0 + kq*4];
            st[row*33 + kq*4 + 0] = v.x;
            st[row*33 + kq*4 + 1] = v.y;
            st[row*33 + kq*4 + 2] = v.z;
            st[row*33 + kq*4 + 3] = v.w;
        }
        for (int e = t; e < 512; e += 256) {
            int kk = e >> 4, c4 = e & 15;
            int col = c0 + c4*4;
            const float* W; int ncol, cb;
            if (col < 192)      { W = Wq;   ncol = 192; cb = 0; }
            else if (col < 576) { W = Wkv;  ncol = 384; cb = 192; }
            else if (col < 720) { W = Wqp;  ncol = 144; cb = 576; }
            else                { W = Wkvp; ncol = 432; cb = 720; }
            float4 v = *(const float4*)&W[(size_t)(k0 + kk)*ncol + (col - cb)];
            *(float4*)&wt[kk*64 + c4*4] = v;
        }
        __syncthreads();

#pragma unroll 8
        for (int kk = 0; kk < 32; ++kk) {
            float4 w = *(const float4*)&wt[kk*64 + tc*4];
            float sv[4];
#pragma unroll
            for (int r = 0; r < 4; ++r) sv[r] = st[(tm*4 + r)*33 + kk];
#pragma unroll
            for (int r = 0; r < 4; ++r) {
                acc[r][0] += sv[r] * w.x;
                acc[r][1] += sv[r] * w.y;
                acc[r][2] += sv[r] * w.z;
                acc[r][3] += sv[r] * w.w;
            }
        }
    }

    float* slab = raw_out + (size_t)kc*N*NRAW;
#pragma unroll
    for (int r = 0; r < 4; ++r) {
        float4 o = make_float4(acc[r][0], acc[r][1], acc[r][2], acc[r][3]);
        *(float4*)&slab[(size_t)(m0 + tm*4 + r)*NRAW + c0 + tc*4] = o;
    }
}

// ---------------------------------------------------------------------------
// Kernel 1b: sum 3 raw slabs (float4) + rotary + rigid-frame transforms.
// One block per residue n. Block 0 -> wbT.
// ---------------------------------------------------------------------------
__global__ __launch_bounds__(256) void k_post(
    const float* __restrict__ raw_in, const float* __restrict__ rot,
    const float* __restrict__ trans, const float* __restrict__ Wb,
    float* __restrict__ ws)
{
    const int n = blockIdx.x;
    const int t = threadIdx.x;
    __shared__ float raw[NRAW];

    for (int e4 = t; e4 < NRAW/4; e4 += 256) {   // 288 float4s, 2 sweeps
        float4 a0 = *(const float4*)&raw_in[((size_t)n)*NRAW + e4*4];
        float4 a1 = *(const float4*)&raw_in[((size_t)(N + n))*NRAW + e4*4];
        float4 a2 = *(const float4*)&raw_in[((size_t)(2*N + n))*NRAW + e4*4];
        float4 r4 = make_float4(a0.x + a1.x + a2.x, a0.y + a1.y + a2.y,
                                a0.z + a1.z + a2.z, a0.w + a1.w + a2.w);
        *(float4*)&raw[e4*4] = r4;
    }
    __syncthreads();

    if (n == 0) {
        for (int idx = t; idx < H*C_Z; idx += 256) {
            int h = idx >> 7, c = idx & 127;
            ws[WS_WBT + h*128 + c] = Wb[c*H + h];
        }
    }

    float R[9], T[3];
#pragma unroll
    for (int u = 0; u < 9; ++u) R[u] = rot[n*9 + u];
#pragma unroll
    for (int u = 0; u < 3; ++u) T[u] = trans[n*3 + u];

    float* q    = ws + WS_Q;
    float* v    = ws + WS_V;
    float* qp   = ws + WS_QP;
    float* vp   = ws + WS_VP;
    float* kT4  = ws + WS_KT;
    float* kpT4 = ws + WS_KPT;

    for (int idx = t; idx < 1152; idx += 256) {
        if (idx < 192) {
            int h = idx >> 4, c = idx & 15;
            float val;
            if (c < 8) {
                int f = c >> 1;
                float fr = (f == 0) ? 1.0f : (f == 1) ? 0.1f : (f == 2) ? 0.01f : 0.001f;
                float ang = (float)n * fr;
                float x1 = raw[h*16 + 2*f];
                float x2 = raw[h*16 + 2*f + 1];
                float cs = cosf(ang), sn = sinf(ang);
                val = (c & 1) ? (x1*sn + x2*cs) : (x1*cs - x2*sn);
            } else {
                val = raw[h*16 + c];
            }
            q[n*192 + idx] = val;
        } else if (idx < 384) {
            int o = idx - 192, h = o >> 4, c = o & 15;
            float val;
            if (c < 8) {
                int f = c >> 1;
                float fr = (f == 0) ? 1.0f : (f == 1) ? 0.1f : (f == 2) ? 0.01f : 0.001f;
                float ang = (float)n * fr;
                float x1 = raw[192 + h*32 + 2*f];
                float x2 = raw[192 + h*32 + 2*f + 1];
                float cs = cosf(ang), sn = sinf(ang);
                val = (c & 1) ? (x1*sn + x2*cs) : (x1*cs - x2*sn);
            } else {
                val = raw[192 + h*32 + c];
            }
            kT4[((size_t)(o >> 2)*N + n)*4 + (o & 3)] = val;
        } else if (idx < 576) {
            int o = idx - 384, h = o >> 4, c = o & 15;
            v[n*192 + o] = raw[192 + h*32 + 16 + c];
        } else if (idx < 720) {
            int o = idx - 576;
            int hp = o / 3, ic = o - hp*3;
            float acc = T[ic];
#pragma unroll
            for (int j = 0; j < 3; ++j) acc += R[ic*3 + j] * raw[576 + j*48 + hp];
            qp[n*144 + o] = acc;
        } else {
            int o = idx - 720;
            int hp = o / 3, ic = o - hp*3;
            int h = hp / 12, p = hp - h*12;
            float acc = T[ic];
#pragma unroll
            for (int j = 0; j < 3; ++j) acc += R[ic*3 + j] * raw[720 + j*144 + hp];
            if (p < PQ) {
                int e = h*12 + p*3 + ic;
                kpT4[((size_t)(e >> 2)*N + n)*4 + (e & 3)] = acc;
            } else {
                vp[n*(H*PV*3) + (h*PV + (p - PQ))*3 + ic] = acc;
            }
        }
    }
}

// ---------------------------------------------------------------------------
// Kernel 2: raw logits + per-tile softmax stats. Grid (N, 8). Half-sized zt.
// ---------------------------------------------------------------------------
__global__ __launch_bounds__(256) void k_logits(
    float* __restrict__ ws, const float* __restrict__ z,
    const float* __restrict__ bb,
    const float* __restrict__ hwts, const float* __restrict__ mask,
    float* __restrict__ a_out)
{
    const int i  = blockIdx.x;
    const int j0 = blockIdx.y * 64;
    const int t  = threadIdx.x;
    const int j  = t & 63;
    const int jg = j0 + j;
    const int h0 = __builtin_amdgcn_readfirstlane(3 * (t >> 6));

    __shared__ float zt[64*68];

    float4 ra0, ra1, ra2, ra3, rb0, rb1, rb2, rb3;
    {
        const float* zbase = z + (((size_t)i*N) + j0)*C_Z;
        int e0 = t,       r0_ = e0 >> 4, c0_ = e0 & 15;
        int e1 = t + 256, r1_ = e1 >> 4, c1_ = e1 & 15;
        int e2 = t + 512, r2_ = e2 >> 4, c2_ = e2 & 15;
        int e3 = t + 768, r3_ = e3 >> 4, c3_ = e3 & 15;
        ra0 = *(const float4*)&zbase[(size_t)r0_*C_Z + c0_*4];
        ra1 = *(const float4*)&zbase[(size_t)r1_*C_Z + c1_*4];
        ra2 = *(const float4*)&zbase[(size_t)r2_*C_Z + c2_*4];
        ra3 = *(const float4*)&zbase[(size_t)r3_*C_Z + c3_*4];
        rb0 = *(const float4*)&zbase[(size_t)r0_*C_Z + 64 + c0_*4];
        rb1 = *(const float4*)&zbase[(size_t)r1_*C_Z + 64 + c1_*4];
        rb2 = *(const float4*)&zbase[(size_t)r2_*C_Z + 64 + c2_*4];
        rb3 = *(const float4*)&zbase[(size_t)r3_*C_Z + 64 + c3_*4];
    }

    const float* q    = ws + WS_Q  + (size_t)i*192;
    const float* qp   = ws + WS_QP + (size_t)i*144;
    const float* kT4  = ws + WS_KT;
    const float* kpT4 = ws + WS_KPT;

    const float c1 = sqrtf(1.0f / 48.0f);
    const float c2 = sqrtf(1.0f / 3.0f);
    const float mterm = 100000.0f * (mask[i] * mask[jg] - 1.0f);

    float qkd[3];
#pragma unroll
    for (int u = 0; u < 3; ++u) {
        const int h = h0 + u;
        float qk = 0.0f;
#pragma unroll
        for (int cq = 0; cq < 4; ++cq) {
            float4 kv = *(const float4*)&kT4[((size_t)(h*4 + cq)*N + jg)*4];
            qk += q[h*16 + cq*4 + 0]*kv.x + q[h*16 + cq*4 + 1]*kv.y
                + q[h*16 + cq*4 + 2]*kv.z + q[h*16 + cq*4 + 3]*kv.w;
        }
        float d2s = 0.0f;
#pragma unroll
        for (int eq = 0; eq < 3; ++eq) {
            float4 pv = *(const float4*)&kpT4[((size_t)(h*3 + eq)*N + jg)*4];
            float d;
            d = qp[h*12 + eq*4 + 0] - pv.x; d2s += d*d;
            d = qp[h*12 + eq*4 + 1] - pv.y; d2s += d*d;
            d = qp[h*12 + eq*4 + 2] - pv.z; d2s += d*d;
            d = qp[h*12 + eq*4 + 3] - pv.w; d2s += d*d;
        }
        float hw = log1pf(expf(hwts[h])) * sqrtf(1.0f / 54.0f);
        qkd[u] = c1*qk - 0.5f*hw*d2s + mterm + c2*bb[h];
    }

    {
        int e0 = t,       r0_ = e0 >> 4, c0_ = e0 & 15;
        int e1 = t + 256, r1_ = e1 >> 4, c1_ = e1 & 15;
        int e2 = t + 512, r2_ = e2 >> 4, c2_ = e2 & 15;
        int e3 = t + 768, r3_ = e3 >> 4, c3_ = e3 & 15;
        *(float4*)&zt[r0_*68 + c0_*4] = ra0;
        *(float4*)&zt[r1_*68 + c1_*4] = ra1;
        *(float4*)&zt[r2_*68 + c2_*4] = ra2;
        *(float4*)&zt[r3_*68 + c3_*4] = ra3;
    }
    __syncthreads();

    const float* w0 = ws + WS_WBT + (size_t)h0*128;
    float acc[3] = {0.0f, 0.0f, 0.0f};
#pragma unroll
    for (int c4 = 0; c4 < 16; ++c4) {
        float4 zv = *(const float4*)&zt[j*68 + c4*4];
        float4 b0 = *(const float4*)&w0[c4*4];
        float4 b1 = *(const float4*)&w0[128 + c4*4];
        float4 b2 = *(const float4*)&w0[256 + c4*4];
        acc[0] += zv.x*b0.x + zv.y*b0.y + zv.z*b0.z + zv.w*b0.w;
        acc[1] += zv.x*b1.x + zv.y*b1.y + zv.z*b1.z + zv.w*b1.w;
        acc[2] += zv.x*b2.x + zv.y*b2.y + zv.z*b2.z + zv.w*b2.w;
    }
    __syncthreads();

    {
        int e0 = t,       r0_ = e0 >> 4, c0_ = e0 & 15;
        int e1 = t + 256, r1_ = e1 >> 4, c1_ = e1 & 15;
        int e2 = t + 512, r2_ = e2 >> 4, c2_ = e2 & 15;
        int e3 = t + 768, r3_ = e3 >> 4, c3_ = e3 & 15;
        *(float4*)&zt[r0_*68 + c0_*4] = rb0;
        *(float4*)&zt[r1_*68 + c1_*4] = rb1;
        *(float4*)&zt[r2_*68 + c2_*4] = rb2;
        *(float4*)&zt[r3_*68 + c3_*4] = rb3;
    }
    __syncthreads();

#pragma unroll
    for (int c4 = 0; c4 < 16; ++c4) {
        float4 zv = *(const float4*)&zt[j*68 + c4*4];
        float4 b0 = *(const float4*)&w0[64 + c4*4];
        float4 b1 = *(const float4*)&w0[192 + c4*4];
        float4 b2 = *(const float4*)&w0[320 + c4*4];
        acc[0] += zv.x*b0.x + zv.y*b0.y + zv.z*b0.z + zv.w*b0.w;
        acc[1] += zv.x*b1.x + zv.y*b1.y + zv.z*b1.z + zv.w*b1.w;
        acc[2] += zv.x*b2.x + zv.y*b2.y + zv.z*b2.z + zv.w*b2.w;
    }

    float lgv[3];
#pragma unroll
    for (int u = 0; u < 3; ++u) {
        lgv[u] = qkd[u] + c2*acc[u];
        a_out[((size_t)(h0 + u)*N + i)*N + jg] = lgv[u];
    }

    float* sm = ws + WS_SM;
#pragma unroll
    for (int u = 0; u < 3; ++u) {
        float m = lgv[u];
#pragma unroll
        for (int off = 32; off; off >>= 1) m = fmaxf(m, __shfl_xor(m, off));
        float sme = expf(lgv[u] - m);
#pragma unroll
        for (int off = 32; off; off >>= 1) sme += __shfl_xor(sme, off);
        if (j == 0) {
            sm[(size_t)i*192 + (h0 + u)*16 + blockIdx.y*2 + 0] = m;
            sm[(size_t)i*192 + (h0 + u)*16 + blockIdx.y*2 + 1] = sme;
        }
    }
}

// ---------------------------------------------------------------------------
// Kernel 3a: merge stats, normalize a on load (write back), partials.
// Grid (N, NJC). Phase A: float2-paired outputs, single sweep, unified loop.
// Phase B: float2 z-loads, 4 head-groups of 3.
// ---------------------------------------------------------------------------
__global__ __launch_bounds__(256) void k_av(
    float* __restrict__ a_full, const float* __restrict__ ws_ro,
    const float* __restrict__ z, float* __restrict__ ws)
{
    const int i  = blockIdx.x;
    const int jc = blockIdx.y;
    const int j0 = jc * JCHUNK;
    const int t  = threadIdx.x;

    __shared__ float a_s[H*JCHUNK];
    __shared__ float Msm[12], Ism[12];

    const float* v  = ws_ro + WS_V;
    const float* vp = ws_ro + WS_VP;
    const float* sm = ws_ro + WS_SM;
    float* part = ws + WS_PART + ((size_t)i*NJC + jc)*NPART;

    if (t < 12) {
        const float* st = sm + (size_t)i*192 + t*16;
        float M = -1e30f;
#pragma unroll
        for (int q8 = 0; q8 < 8; ++q8) M = fmaxf(M, st[q8*2]);
        float S = 0.0f;
#pragma unroll
        for (int q8 = 0; q8 < 8; ++q8) S += st[q8*2 + 1] * expf(st[q8*2] - M);
        Msm[t] = M;
        Ism[t] = 1.0f / S;
    }
    __syncthreads();

    for (int e = t; e < H*JCHUNK; e += 256) {
        int h = e >> 7, jj = e & (JCHUNK-1);
        size_t gi = ((size_t)h*N + i)*N + j0 + jj;
        float val = expf(a_full[gi] - Msm[h]) * Ism[h];
        a_s[e] = val;
        a_full[gi] = val;
    }
    __syncthreads();

    // Phase A: 240 float2-paired outputs (o: pairs 0..95, o_pt: pairs 96..239)
    if (t < 240) {
        const float* src; int h, stride, dst;
        if (t < 96) {
            int o = 2*t;
            src = v + (size_t)j0*192 + o; stride = 192; h = o >> 4; dst = o;
        } else {
            int o = 2*(t - 96);
            src = vp + (size_t)j0*288 + o; stride = 288; h = (o/3) >> 3; dst = 192 + o;
        }
        const float* ar = &a_s[h*JCHUNK];
        float accx = 0.0f, accy = 0.0f;
#pragma unroll 8
        for (int jj = 0; jj < JCHUNK; ++jj) {
            float2 vv = *(const float2*)&src[(size_t)jj*stride];
            float av = ar[jj];
            accx += av * vv.x;
            accy += av * vv.y;
        }
        part[dst]     = accx;
        part[dst + 1] = accy;
    }

    {
        const int c2 = t & 63;        // c = 2*c2, 2*c2+1
        const int hb = t >> 6;        // 0..3, heads hb*3 + u
        float acc0[3] = {0,0,0}, acc1[3] = {0,0,0};
        const float* zi = z + ((size_t)i*N + j0)*C_Z + 2*c2;
#pragma unroll 4
        for (int jj = 0; jj < JCHUNK; jj += 4) {
            float2 z0 = *(const float2*)&zi[(size_t)(jj+0)*C_Z];
            float2 z1 = *(const float2*)&zi[(size_t)(jj+1)*C_Z];
            float2 z2 = *(const float2*)&zi[(size_t)(jj+2)*C_Z];
            float2 z3 = *(const float2*)&zi[(size_t)(jj+3)*C_Z];
            float4 av[3];
#pragma unroll
            for (int u = 0; u < 3; ++u)
                av[u] = *(const float4*)&a_s[(hb*3 + u)*JCHUNK + jj];
#pragma unroll
            for (int u = 0; u < 3; ++u) {
                acc0[u] += av[u].x*z0.x + av[u].y*z1.x + av[u].z*z2.x + av[u].w*z3.x;
                acc1[u] += av[u].x*z0.y + av[u].y*z1.y + av[u].z*z2.y + av[u].w*z3.y;
            }
        }
#pragma unroll
        for (int u = 0; u < 3; ++u) {
            part[480 + (hb*3 + u)*C_Z + 2*c2 + 0] = acc0[u];
            part[480 + (hb*3 + u)*C_Z + 2*c2 + 1] = acc1[u];
        }
    }
}

// ---------------------------------------------------------------------------
// Kernel 3b: reduce partials (float4), inverse-frame rotation, norms -> feat.
// ---------------------------------------------------------------------------
__global__ __launch_bounds__(256) void k_feat(
    const float* __restrict__ rot, const float* __restrict__ trans,
    float* __restrict__ ws)
{
    const int i = blockIdx.x;
    const int t = threadIdx.x;

    __shared__ float vec[NPART];

    const float* part = ws + WS_PART + (size_t)i*NJC*NPART;
    float* feat = ws + WS_FEAT + (size_t)i*NFEAT;

    for (int e4 = t; e4 < 504; e4 += 256) {
        float4 acc = make_float4(0.f, 0.f, 0.f, 0.f);
#pragma unroll
        for (int jc = 0; jc < NJC; ++jc) {
            float4 p = *(const float4*)&part[(size_t)jc*NPART + e4*4];
            acc.x += p.x; acc.y += p.y; acc.z += p.z; acc.w += p.w;
        }
        *(float4*)&vec[e4*4] = acc;
    }
    __syncthreads();

    for (int e = t; e < NPART; e += 256) {
        if (e < 192)       feat[e] = vec[e];
        else if (e >= 480) feat[192 + (e - 480)] = vec[e];
    }

    if (t < H*PV) {
        const int hp = t;
        float T0 = trans[i*3+0], T1 = trans[i*3+1], T2 = trans[i*3+2];
        float px = vec[192 + hp*3 + 0] - T0;
        float py = vec[192 + hp*3 + 1] - T1;
        float pz = vec[192 + hp*3 + 2] - T2;
        const float* R = rot + i*9;
        float ox = R[0]*px + R[3]*py + R[6]*pz;
        float oy = R[1]*px + R[4]*py + R[7]*pz;
        float oz = R[2]*px + R[5]*py + R[8]*pz;
        feat[1728 + hp]       = ox;
        feat[1728 + 96 + hp]  = oy;
        feat[1728 + 192 + hp] = oz;
        feat[2016 + hp] = sqrtf(ox*ox + oy*oy + oz*oz + 1e-8f);
    }
}

// ---------------------------------------------------------------------------
// Kernel 3c: split-K GEMM partials. Grid (8, 6, KSPLIT).
// ---------------------------------------------------------------------------
__global__ __launch_bounds__(256) void k_final_part(
    const float* __restrict__ ws,
    const float* __restrict__ Whid, const float* __restrict__ Wpair,
    const float* __restrict__ Wpts, const float* __restrict__ Wpn,
    float* __restrict__ fout)
{
    const int m0 = blockIdx.x * 64;
    const int c0 = blockIdx.y * 64;
    const int kc = blockIdx.z;
    const int t  = threadIdx.x;
    const int tc = t & 15;
    const int tm = t >> 4;

    __shared__ float ft[64 * 33];
    __shared__ float wt[32 * 64];

    const float* feat = ws + WS_FEAT;

    float acc[4][4];
#pragma unroll
    for (int r = 0; r < 4; ++r)
#pragma unroll
        for (int u = 0; u < 4; ++u) acc[r][u] = 0.0f;

    const int kbase = kc * KCHUNK;
    for (int k0 = kbase; k0 < kbase + KCHUNK; k0 += 32) {
        const float* W; int r0;
        if (k0 < 192)       { W = Whid;  r0 = k0; }
        else if (k0 < 1728) { W = Wpair; r0 = k0 - 192; }
        else if (k0 < 2016) { W = Wpts;  r0 = k0 - 1728; }
        else                { W = Wpn;   r0 = k0 - 2016; }

        __syncthreads();
        for (int e = t; e < 512; e += 256) {
            int row = e >> 3, kq = e & 7;
            float4 v = *(const float4*)&feat[(size_t)(m0 + row)*NFEAT + k0 + kq*4];
            ft[row*33 + kq*4 + 0] = v.x;
            ft[row*33 + kq*4 + 1] = v.y;
            ft[row*33 + kq*4 + 2] = v.z;
            ft[row*33 + kq*4 + 3] = v.w;
        }
        for (int e = t; e < 512; e += 256) {
            int kk = e >> 4, c4 = e & 15;
            float4 v = *(const float4*)&W[(size_t)(r0 + kk)*C_S + c0 + c4*4];
            *(float4*)&wt[kk*64 + c4*4] = v;
        }
        __syncthreads();

#pragma unroll 8
        for (int kk = 0; kk < 32; ++kk) {
            float4 w = *(const float4*)&wt[kk*64 + tc*4];
            float sv[4];
#pragma unroll
            for (int r = 0; r < 4; ++r) sv[r] = ft[(tm*4 + r)*33 + kk];
#pragma unroll
            for (int r = 0; r < 4; ++r) {
                acc[r][0] += sv[r] * w.x;
                acc[r][1] += sv[r] * w.y;
                acc[r][2] += sv[r] * w.z;
                acc[r][3] += sv[r] * w.w;
            }
        }
    }

#pragma unroll
    for (int r = 0; r < 4; ++r) {
        float4 o = make_float4(acc[r][0], acc[r][1], acc[r][2], acc[r][3]);
        *(float4*)&fout[((size_t)kc*N + m0 + tm*4 + r)*C_S + c0 + tc*4] = o;
    }
}

// ---------------------------------------------------------------------------
// Kernel 3d: reduce split-K partials + bias -> s_out. 768 blocks x 256.
// ---------------------------------------------------------------------------
__global__ __launch_bounds__(256) void k_red(
    const float* __restrict__ fout,
    const float* __restrict__ bhid, const float* __restrict__ bpair,
    const float* __restrict__ bpts, const float* __restrict__ bpn,
    float* __restrict__ s_out)
{
    const int idx = blockIdx.x * 256 + threadIdx.x;
    const int c = idx % C_S;
    float acc = bhid[c] + bpair[c] + bpts[c] + bpn[c];
#pragma unroll
    for (int kc = 0; kc < KSPLIT; ++kc)
        acc += fout[(size_t)kc*N*C_S + idx];
    s_out[idx] = acc;
}

extern "C" void kernel_launch(void* const* d_in, const int* in_sizes, int n_in,
                              void* d_out, int out_size, void* d_ws, size_t ws_size,
                              hipStream_t stream) {
    const float* s     = (const float*)d_in[0];
    const float* z     = (const float*)d_in[1];
    const float* rot   = (const float*)d_in[2];
    const float* trans = (const float*)d_in[3];
    const float* mask  = (const float*)d_in[4];
    const float* Wq    = (const float*)d_in[5];
    const float* bq    = (const float*)d_in[6];
    const float* Wkv   = (const float*)d_in[7];
    const float* bkv   = (const float*)d_in[8];
    const float* Wqp   = (const float*)d_in[9];
    const float* bqp   = (const float*)d_in[10];
    const float* Wkvp  = (const float*)d_in[11];
    const float* bkvp  = (const float*)d_in[12];
    const float* Wb    = (const float*)d_in[13];
    const float* bb    = (const float*)d_in[14];
    const float* hwts  = (const float*)d_in[15];
    const float* Whid  = (const float*)d_in[16];
    const float* bhid  = (const float*)d_in[17];
    const float* Wpair = (const float*)d_in[18];
    const float* bpair = (const float*)d_in[19];
    const float* Wpts  = (const float*)d_in[20];
    const float* bpts  = (const float*)d_in[21];
    const float* Wpn   = (const float*)d_in[22];
    const float* bpn   = (const float*)d_in[23];

    float* out   = (float*)d_out;
    float* s_out = out;                 // 512*384
    float* a_out = out + N*C_S;         // 12*512*512
    float* ws    = (float*)d_ws;

    k_gemm_proj<<<dim3(8, 18, PSPLIT), 256, 0, stream>>>(s, Wq, bq, Wkv, bkv,
                                                         Wqp, bqp, Wkvp, bkvp,
                                                         ws + WS_RAW);
    k_post<<<N, 256, 0, stream>>>(ws + WS_RAW, rot, trans, Wb, ws);
    k_logits<<<dim3(N, 8), 256, 0, stream>>>(ws, z, bb, hwts, mask, a_out);
    k_av<<<dim3(N, NJC), 256, 0, stream>>>(a_out, ws, z, ws);
    k_feat<<<N, 256, 0, stream>>>(rot, trans, ws);
    k_final_part<<<dim3(8, 6, KSPLIT), 256, 0, stream>>>(ws, Whid, Wpair, Wpts,
                                                         Wpn, ws + WS_FOUT);
    k_red<<<(N*C_S)/256, 256, 0, stream>>>(ws + WS_FOUT, bhid, bpair, bpts, bpn,
                                           s_out);
}

// Round 20
// 148.594 us; speedup vs baseline: 1.0627x; 1.0627x over previous
//
#include <hip/hip_runtime.h>
#include <hip/hip_bf16.h>
#include <cmath>

#define N 512
#define C_S 384
#define C_Z 128
#define C_H 16
#define H 12
#define PQ 4
#define PV 8

#define NJC 4            // j-split chunks in k_av
#define JCHUNK (N / NJC) // 128
#define NPART 2016       // per (i,jc) partial vector: o(192) + o_pt(288) + o_pair(1536)
#define NFEAT 2112       // o(192) + o_pair(1536) + ptsf(288) + pnorm(96)
#define NRAW 1152        // q(192) + kv(384) + qp(144) + kvp(432)
#define KSPLIT 11        // k-chunks in k_final_part (2112 = 11*192)
#define KCHUNK 192
#define PSPLIT 3         // split-K in k_gemm_proj (384 = 3*128)

// workspace layout (floats)
#define WS_Q    0
#define WS_K    (WS_Q + N*H*C_H)
#define WS_SM   WS_K                          // 512*192 floats (tile softmax stats)
#define WS_V    (WS_K + N*H*C_H)
#define WS_QP   (WS_V + N*H*C_H)
#define WS_KP   (WS_QP + N*H*PQ*3)
#define WS_VP   (WS_KP + N*H*PQ*3)
#define WS_PART (WS_VP + N*H*PV*3)            // 512*4*2016 floats
#define WS_FEAT (WS_PART + N*NJC*NPART)       // 512*2112 floats
#define WS_RAW  WS_PART                       // raw partials [3][512][1152]; consumed by k_post
#define WS_KT   (WS_PART + 2000000)           // kT4[48][512][4]; live k_post -> k_logits
#define WS_KPT  (WS_KT + 98304)               // kpT4[36][512][4]; live k_post -> k_logits
#define WS_WBT  (WS_KPT + 73728)              // wbT[12][128]; live k_post -> k_logits
#define WS_FOUT WS_PART                       // fout[11][512][384]; dead after k_feat

// ---------------------------------------------------------------------------
// Kernel 1a: raw projections, split-K GEMM. Grid (8, 18, 3).
// ---------------------------------------------------------------------------
__global__ __launch_bounds__(256) void k_gemm_proj(
    const float* __restrict__ s,
    const float* __restrict__ Wq,  const float* __restrict__ bq,
    const float* __restrict__ Wkv, const float* __restrict__ bkv,
    const float* __restrict__ Wqp, const float* __restrict__ bqp,
    const float* __restrict__ Wkvp,const float* __restrict__ bkvp,
    float* __restrict__ raw_out)
{
    const int m0 = blockIdx.x * 64;
    const int c0 = blockIdx.y * 64;
    const int kc = blockIdx.z;
    const int t  = threadIdx.x;
    const int tc = t & 15;
    const int tm = t >> 4;

    __shared__ float st[64 * 33];
    __shared__ float wt[32 * 64];

    float acc[4][4];
    if (kc == 0) {
#pragma unroll
        for (int u = 0; u < 4; ++u) {
            int col = c0 + tc*4 + u;
            const float* b; int cb;
            if (col < 192)      { b = bq;   cb = 0; }
            else if (col < 576) { b = bkv;  cb = 192; }
            else if (col < 720) { b = bqp;  cb = 576; }
            else                { b = bkvp; cb = 720; }
            float bv = b[col - cb];
#pragma unroll
            for (int r = 0; r < 4; ++r) acc[r][u] = bv;
        }
    } else {
#pragma unroll
        for (int u = 0; u < 4; ++u)
#pragma unroll
            for (int r = 0; r < 4; ++r) acc[r][u] = 0.0f;
    }

    const int kbase = kc * 128;
    for (int k0 = kbase; k0 < kbase + 128; k0 += 32) {
        __syncthreads();
        for (int e = t; e < 512; e += 256) {
            int row = e >> 3, kq = e & 7;
            float4 v = *(const float4*)&s[(size_t)(m0 + row)*C_S + k0 + kq*4];
            st[row*33 + kq*4 + 0] = v.x;
            st[row*33 + kq*4 + 1] = v.y;
            st[row*33 + kq*4 + 2] = v.z;
            st[row*33 + kq*4 + 3] = v.w;
        }
        for (int e = t; e < 512; e += 256) {
            int kk = e >> 4, c4 = e & 15;
            int col = c0 + c4*4;
            const float* W; int ncol, cb;
            if (col < 192)      { W = Wq;   ncol = 192; cb = 0; }
            else if (col < 576) { W = Wkv;  ncol = 384; cb = 192; }
            else if (col < 720) { W = Wqp;  ncol = 144; cb = 576; }
            else                { W = Wkvp; ncol = 432; cb = 720; }
            float4 v = *(const float4*)&W[(size_t)(k0 + kk)*ncol + (col - cb)];
            *(float4*)&wt[kk*64 + c4*4] = v;
        }
        __syncthreads();

#pragma unroll 8
        for (int kk = 0; kk < 32; ++kk) {
            float4 w = *(const float4*)&wt[kk*64 + tc*4];
            float sv[4];
#pragma unroll
            for (int r = 0; r < 4; ++r) sv[r] = st[(tm*4 + r)*33 + kk];
#pragma unroll
            for (int r = 0; r < 4; ++r) {
                acc[r][0] += sv[r] * w.x;
                acc[r][1] += sv[r] * w.y;
                acc[r][2] += sv[r] * w.z;
                acc[r][3] += sv[r] * w.w;
            }
        }
    }

    float* slab = raw_out + (size_t)kc*N*NRAW;
#pragma unroll
    for (int r = 0; r < 4; ++r) {
        float4 o = make_float4(acc[r][0], acc[r][1], acc[r][2], acc[r][3]);
        *(float4*)&slab[(size_t)(m0 + tm*4 + r)*NRAW + c0 + tc*4] = o;
    }
}

// ---------------------------------------------------------------------------
// Kernel 1b: sum 3 raw slabs (float4) + rotary + rigid-frame transforms.
// One block per residue n. Block 0 -> wbT.
// ---------------------------------------------------------------------------
__global__ __launch_bounds__(256) void k_post(
    const float* __restrict__ raw_in, const float* __restrict__ rot,
    const float* __restrict__ trans, const float* __restrict__ Wb,
    float* __restrict__ ws)
{
    const int n = blockIdx.x;
    const int t = threadIdx.x;
    __shared__ float raw[NRAW];

    for (int e4 = t; e4 < NRAW/4; e4 += 256) {   // 288 float4s, 2 sweeps
        float4 a0 = *(const float4*)&raw_in[((size_t)n)*NRAW + e4*4];
        float4 a1 = *(const float4*)&raw_in[((size_t)(N + n))*NRAW + e4*4];
        float4 a2 = *(const float4*)&raw_in[((size_t)(2*N + n))*NRAW + e4*4];
        float4 r4 = make_float4(a0.x + a1.x + a2.x, a0.y + a1.y + a2.y,
                                a0.z + a1.z + a2.z, a0.w + a1.w + a2.w);
        *(float4*)&raw[e4*4] = r4;
    }
    __syncthreads();

    if (n == 0) {
        for (int idx = t; idx < H*C_Z; idx += 256) {
            int h = idx >> 7, c = idx & 127;
            ws[WS_WBT + h*128 + c] = Wb[c*H + h];
        }
    }

    float R[9], T[3];
#pragma unroll
    for (int u = 0; u < 9; ++u) R[u] = rot[n*9 + u];
#pragma unroll
    for (int u = 0; u < 3; ++u) T[u] = trans[n*3 + u];

    float* q    = ws + WS_Q;
    float* v    = ws + WS_V;
    float* qp   = ws + WS_QP;
    float* vp   = ws + WS_VP;
    float* kT4  = ws + WS_KT;
    float* kpT4 = ws + WS_KPT;

    for (int idx = t; idx < 1152; idx += 256) {
        if (idx < 192) {
            int h = idx >> 4, c = idx & 15;
            float val;
            if (c < 8) {
                int f = c >> 1;
                float fr = (f == 0) ? 1.0f : (f == 1) ? 0.1f : (f == 2) ? 0.01f : 0.001f;
                float ang = (float)n * fr;
                float x1 = raw[h*16 + 2*f];
                float x2 = raw[h*16 + 2*f + 1];
                float cs = cosf(ang), sn = sinf(ang);
                val = (c & 1) ? (x1*sn + x2*cs) : (x1*cs - x2*sn);
            } else {
                val = raw[h*16 + c];
            }
            q[n*192 + idx] = val;
        } else if (idx < 384) {
            int o = idx - 192, h = o >> 4, c = o & 15;
            float val;
            if (c < 8) {
                int f = c >> 1;
                float fr = (f == 0) ? 1.0f : (f == 1) ? 0.1f : (f == 2) ? 0.01f : 0.001f;
                float ang = (float)n * fr;
                float x1 = raw[192 + h*32 + 2*f];
                float x2 = raw[192 + h*32 + 2*f + 1];
                float cs = cosf(ang), sn = sinf(ang);
                val = (c & 1) ? (x1*sn + x2*cs) : (x1*cs - x2*sn);
            } else {
                val = raw[192 + h*32 + c];
            }
            kT4[((size_t)(o >> 2)*N + n)*4 + (o & 3)] = val;
        } else if (idx < 576) {
            int o = idx - 384, h = o >> 4, c = o & 15;
            v[n*192 + o] = raw[192 + h*32 + 16 + c];
        } else if (idx < 720) {
            int o = idx - 576;
            int hp = o / 3, ic = o - hp*3;
            float acc = T[ic];
#pragma unroll
            for (int j = 0; j < 3; ++j) acc += R[ic*3 + j] * raw[576 + j*48 + hp];
            qp[n*144 + o] = acc;
        } else {
            int o = idx - 720;
            int hp = o / 3, ic = o - hp*3;
            int h = hp / 12, p = hp - h*12;
            float acc = T[ic];
#pragma unroll
            for (int j = 0; j < 3; ++j) acc += R[ic*3 + j] * raw[720 + j*144 + hp];
            if (p < PQ) {
                int e = h*12 + p*3 + ic;
                kpT4[((size_t)(e >> 2)*N + n)*4 + (e & 3)] = acc;
            } else {
                vp[n*(H*PV*3) + (h*PV + (p - PQ))*3 + ic] = acc;
            }
        }
    }
}

// ---------------------------------------------------------------------------
// Kernel 2: raw logits + per-tile softmax stats. Grid (N, 8). Half-sized zt.
// ---------------------------------------------------------------------------
__global__ __launch_bounds__(256) void k_logits(
    float* __restrict__ ws, const float* __restrict__ z,
    const float* __restrict__ bb,
    const float* __restrict__ hwts, const float* __restrict__ mask,
    float* __restrict__ a_out)
{
    const int i  = blockIdx.x;
    const int j0 = blockIdx.y * 64;
    const int t  = threadIdx.x;
    const int j  = t & 63;
    const int jg = j0 + j;
    const int h0 = __builtin_amdgcn_readfirstlane(3 * (t >> 6));

    __shared__ float zt[64*68];

    float4 ra0, ra1, ra2, ra3, rb0, rb1, rb2, rb3;
    {
        const float* zbase = z + (((size_t)i*N) + j0)*C_Z;
        int e0 = t,       r0_ = e0 >> 4, c0_ = e0 & 15;
        int e1 = t + 256, r1_ = e1 >> 4, c1_ = e1 & 15;
        int e2 = t + 512, r2_ = e2 >> 4, c2_ = e2 & 15;
        int e3 = t + 768, r3_ = e3 >> 4, c3_ = e3 & 15;
        ra0 = *(const float4*)&zbase[(size_t)r0_*C_Z + c0_*4];
        ra1 = *(const float4*)&zbase[(size_t)r1_*C_Z + c1_*4];
        ra2 = *(const float4*)&zbase[(size_t)r2_*C_Z + c2_*4];
        ra3 = *(const float4*)&zbase[(size_t)r3_*C_Z + c3_*4];
        rb0 = *(const float4*)&zbase[(size_t)r0_*C_Z + 64 + c0_*4];
        rb1 = *(const float4*)&zbase[(size_t)r1_*C_Z + 64 + c1_*4];
        rb2 = *(const float4*)&zbase[(size_t)r2_*C_Z + 64 + c2_*4];
        rb3 = *(const float4*)&zbase[(size_t)r3_*C_Z + 64 + c3_*4];
    }

    const float* q    = ws + WS_Q  + (size_t)i*192;
    const float* qp   = ws + WS_QP + (size_t)i*144;
    const float* kT4  = ws + WS_KT;
    const float* kpT4 = ws + WS_KPT;

    const float c1 = sqrtf(1.0f / 48.0f);
    const float c2 = sqrtf(1.0f / 3.0f);
    const float mterm = 100000.0f * (mask[i] * mask[jg] - 1.0f);

    float qkd[3];
#pragma unroll
    for (int u = 0; u < 3; ++u) {
        const int h = h0 + u;
        float qk = 0.0f;
#pragma unroll
        for (int cq = 0; cq < 4; ++cq) {
            float4 kv = *(const float4*)&kT4[((size_t)(h*4 + cq)*N + jg)*4];
            qk += q[h*16 + cq*4 + 0]*kv.x + q[h*16 + cq*4 + 1]*kv.y
                + q[h*16 + cq*4 + 2]*kv.z + q[h*16 + cq*4 + 3]*kv.w;
        }
        float d2s = 0.0f;
#pragma unroll
        for (int eq = 0; eq < 3; ++eq) {
            float4 pv = *(const float4*)&kpT4[((size_t)(h*3 + eq)*N + jg)*4];
            float d;
            d = qp[h*12 + eq*4 + 0] - pv.x; d2s += d*d;
            d = qp[h*12 + eq*4 + 1] - pv.y; d2s += d*d;
            d = qp[h*12 + eq*4 + 2] - pv.z; d2s += d*d;
            d = qp[h*12 + eq*4 + 3] - pv.w; d2s += d*d;
        }
        float hw = log1pf(expf(hwts[h])) * sqrtf(1.0f / 54.0f);
        qkd[u] = c1*qk - 0.5f*hw*d2s + mterm + c2*bb[h];
    }

    {
        int e0 = t,       r0_ = e0 >> 4, c0_ = e0 & 15;
        int e1 = t + 256, r1_ = e1 >> 4, c1_ = e1 & 15;
        int e2 = t + 512, r2_ = e2 >> 4, c2_ = e2 & 15;
        int e3 = t + 768, r3_ = e3 >> 4, c3_ = e3 & 15;
        *(float4*)&zt[r0_*68 + c0_*4] = ra0;
        *(float4*)&zt[r1_*68 + c1_*4] = ra1;
        *(float4*)&zt[r2_*68 + c2_*4] = ra2;
        *(float4*)&zt[r3_*68 + c3_*4] = ra3;
    }
    __syncthreads();

    const float* w0 = ws + WS_WBT + (size_t)h0*128;
    float acc[3] = {0.0f, 0.0f, 0.0f};
#pragma unroll
    for (int c4 = 0; c4 < 16; ++c4) {
        float4 zv = *(const float4*)&zt[j*68 + c4*4];
        float4 b0 = *(const float4*)&w0[c4*4];
        float4 b1 = *(const float4*)&w0[128 + c4*4];
        float4 b2 = *(const float4*)&w0[256 + c4*4];
        acc[0] += zv.x*b0.x + zv.y*b0.y + zv.z*b0.z + zv.w*b0.w;
        acc[1] += zv.x*b1.x + zv.y*b1.y + zv.z*b1.z + zv.w*b1.w;
        acc[2] += zv.x*b2.x + zv.y*b2.y + zv.z*b2.z + zv.w*b2.w;
    }
    __syncthreads();

    {
        int e0 = t,       r0_ = e0 >> 4, c0_ = e0 & 15;
        int e1 = t + 256, r1_ = e1 >> 4, c1_ = e1 & 15;
        int e2 = t + 512, r2_ = e2 >> 4, c2_ = e2 & 15;
        int e3 = t + 768, r3_ = e3 >> 4, c3_ = e3 & 15;
        *(float4*)&zt[r0_*68 + c0_*4] = rb0;
        *(float4*)&zt[r1_*68 + c1_*4] = rb1;
        *(float4*)&zt[r2_*68 + c2_*4] = rb2;
        *(float4*)&zt[r3_*68 + c3_*4] = rb3;
    }
    __syncthreads();

#pragma unroll
    for (int c4 = 0; c4 < 16; ++c4) {
        float4 zv = *(const float4*)&zt[j*68 + c4*4];
        float4 b0 = *(const float4*)&w0[64 + c4*4];
        float4 b1 = *(const float4*)&w0[192 + c4*4];
        float4 b2 = *(const float4*)&w0[320 + c4*4];
        acc[0] += zv.x*b0.x + zv.y*b0.y + zv.z*b0.z + zv.w*b0.w;
        acc[1] += zv.x*b1.x + zv.y*b1.y + zv.z*b1.z + zv.w*b1.w;
        acc[2] += zv.x*b2.x + zv.y*b2.y + zv.z*b2.z + zv.w*b2.w;
    }

    float lgv[3];
#pragma unroll
    for (int u = 0; u < 3; ++u) {
        lgv[u] = qkd[u] + c2*acc[u];
        a_out[((size_t)(h0 + u)*N + i)*N + jg] = lgv[u];
    }

    float* sm = ws + WS_SM;
#pragma unroll
    for (int u = 0; u < 3; ++u) {
        float m = lgv[u];
#pragma unroll
        for (int off = 32; off; off >>= 1) m = fmaxf(m, __shfl_xor(m, off));
        float sme = expf(lgv[u] - m);
#pragma unroll
        for (int off = 32; off; off >>= 1) sme += __shfl_xor(sme, off);
        if (j == 0) {
            sm[(size_t)i*192 + (h0 + u)*16 + blockIdx.y*2 + 0] = m;
            sm[(size_t)i*192 + (h0 + u)*16 + blockIdx.y*2 + 1] = sme;
        }
    }
}

// ---------------------------------------------------------------------------
// Kernel 3a: merge stats, normalize a on load (write back), partials.
// Grid (N, NJC). Phase A: round-18 two-sweep form (compile-time strides).
// Phase B: float2 z-loads, 4 head-groups of 3.
// ---------------------------------------------------------------------------
__global__ __launch_bounds__(256) void k_av(
    float* __restrict__ a_full, const float* __restrict__ ws_ro,
    const float* __restrict__ z, float* __restrict__ ws)
{
    const int i  = blockIdx.x;
    const int jc = blockIdx.y;
    const int j0 = jc * JCHUNK;
    const int t  = threadIdx.x;

    __shared__ float a_s[H*JCHUNK];
    __shared__ float Msm[12], Ism[12];

    const float* v  = ws_ro + WS_V;
    const float* vp = ws_ro + WS_VP;
    const float* sm = ws_ro + WS_SM;
    float* part = ws + WS_PART + ((size_t)i*NJC + jc)*NPART;

    if (t < 12) {
        const float* st = sm + (size_t)i*192 + t*16;
        float M = -1e30f;
#pragma unroll
        for (int q8 = 0; q8 < 8; ++q8) M = fmaxf(M, st[q8*2]);
        float S = 0.0f;
#pragma unroll
        for (int q8 = 0; q8 < 8; ++q8) S += st[q8*2 + 1] * expf(st[q8*2] - M);
        Msm[t] = M;
        Ism[t] = 1.0f / S;
    }
    __syncthreads();

    for (int e = t; e < H*JCHUNK; e += 256) {
        int h = e >> 7, jj = e & (JCHUNK-1);
        size_t gi = ((size_t)h*N + i)*N + j0 + jj;
        float val = expf(a_full[gi] - Msm[h]) * Ism[h];
        a_s[e] = val;
        a_full[gi] = val;
    }
    __syncthreads();

    for (int idx = t; idx < 480; idx += 256) {
        float acc = 0.0f;
        if (idx < 192) {
            int h = idx >> 4;
            const float* vv = v + (size_t)j0*192 + idx;
            const float* ar = &a_s[h*JCHUNK];
#pragma unroll 8
            for (int jj = 0; jj < JCHUNK; ++jj) acc += ar[jj] * vv[(size_t)jj*192];
        } else {
            int o = idx - 192;
            int h = (o/3) >> 3;
            const float* vv = vp + (size_t)j0*288 + o;
            const float* ar = &a_s[h*JCHUNK];
#pragma unroll 8
            for (int jj = 0; jj < JCHUNK; ++jj) acc += ar[jj] * vv[(size_t)jj*288];
        }
        part[idx] = acc;
    }

    {
        const int c2 = t & 63;        // c = 2*c2, 2*c2+1
        const int hb = t >> 6;        // 0..3, heads hb*3 + u
        float acc0[3] = {0,0,0}, acc1[3] = {0,0,0};
        const float* zi = z + ((size_t)i*N + j0)*C_Z + 2*c2;
#pragma unroll 4
        for (int jj = 0; jj < JCHUNK; jj += 4) {
            float2 z0 = *(const float2*)&zi[(size_t)(jj+0)*C_Z];
            float2 z1 = *(const float2*)&zi[(size_t)(jj+1)*C_Z];
            float2 z2 = *(const float2*)&zi[(size_t)(jj+2)*C_Z];
            float2 z3 = *(const float2*)&zi[(size_t)(jj+3)*C_Z];
            float4 av[3];
#pragma unroll
            for (int u = 0; u < 3; ++u)
                av[u] = *(const float4*)&a_s[(hb*3 + u)*JCHUNK + jj];
#pragma unroll
            for (int u = 0; u < 3; ++u) {
                acc0[u] += av[u].x*z0.x + av[u].y*z1.x + av[u].z*z2.x + av[u].w*z3.x;
                acc1[u] += av[u].x*z0.y + av[u].y*z1.y + av[u].z*z2.y + av[u].w*z3.y;
            }
        }
#pragma unroll
        for (int u = 0; u < 3; ++u) {
            part[480 + (hb*3 + u)*C_Z + 2*c2 + 0] = acc0[u];
            part[480 + (hb*3 + u)*C_Z + 2*c2 + 1] = acc1[u];
        }
    }
}

// ---------------------------------------------------------------------------
// Kernel 3b: reduce partials (float4), inverse-frame rotation, norms -> feat.
// ---------------------------------------------------------------------------
__global__ __launch_bounds__(256) void k_feat(
    const float* __restrict__ rot, const float* __restrict__ trans,
    float* __restrict__ ws)
{
    const int i = blockIdx.x;
    const int t = threadIdx.x;

    __shared__ float vec[NPART];

    const float* part = ws + WS_PART + (size_t)i*NJC*NPART;
    float* feat = ws + WS_FEAT + (size_t)i*NFEAT;

    for (int e4 = t; e4 < 504; e4 += 256) {
        float4 acc = make_float4(0.f, 0.f, 0.f, 0.f);
#pragma unroll
        for (int jc = 0; jc < NJC; ++jc) {
            float4 p = *(const float4*)&part[(size_t)jc*NPART + e4*4];
            acc.x += p.x; acc.y += p.y; acc.z += p.z; acc.w += p.w;
        }
        *(float4*)&vec[e4*4] = acc;
    }
    __syncthreads();

    for (int e = t; e < NPART; e += 256) {
        if (e < 192)       feat[e] = vec[e];
        else if (e >= 480) feat[192 + (e - 480)] = vec[e];
    }

    if (t < H*PV) {
        const int hp = t;
        float T0 = trans[i*3+0], T1 = trans[i*3+1], T2 = trans[i*3+2];
        float px = vec[192 + hp*3 + 0] - T0;
        float py = vec[192 + hp*3 + 1] - T1;
        float pz = vec[192 + hp*3 + 2] - T2;
        const float* R = rot + i*9;
        float ox = R[0]*px + R[3]*py + R[6]*pz;
        float oy = R[1]*px + R[4]*py + R[7]*pz;
        float oz = R[2]*px + R[5]*py + R[8]*pz;
        feat[1728 + hp]       = ox;
        feat[1728 + 96 + hp]  = oy;
        feat[1728 + 192 + hp] = oz;
        feat[2016 + hp] = sqrtf(ox*ox + oy*oy + oz*oz + 1e-8f);
    }
}

// ---------------------------------------------------------------------------
// Kernel 3c: split-K GEMM partials. Grid (8, 6, KSPLIT).
// ---------------------------------------------------------------------------
__global__ __launch_bounds__(256) void k_final_part(
    const float* __restrict__ ws,
    const float* __restrict__ Whid, const float* __restrict__ Wpair,
    const float* __restrict__ Wpts, const float* __restrict__ Wpn,
    float* __restrict__ fout)
{
    const int m0 = blockIdx.x * 64;
    const int c0 = blockIdx.y * 64;
    const int kc = blockIdx.z;
    const int t  = threadIdx.x;
    const int tc = t & 15;
    const int tm = t >> 4;

    __shared__ float ft[64 * 33];
    __shared__ float wt[32 * 64];

    const float* feat = ws + WS_FEAT;

    float acc[4][4];
#pragma unroll
    for (int r = 0; r < 4; ++r)
#pragma unroll
        for (int u = 0; u < 4; ++u) acc[r][u] = 0.0f;

    const int kbase = kc * KCHUNK;
    for (int k0 = kbase; k0 < kbase + KCHUNK; k0 += 32) {
        const float* W; int r0;
        if (k0 < 192)       { W = Whid;  r0 = k0; }
        else if (k0 < 1728) { W = Wpair; r0 = k0 - 192; }
        else if (k0 < 2016) { W = Wpts;  r0 = k0 - 1728; }
        else                { W = Wpn;   r0 = k0 - 2016; }

        __syncthreads();
        for (int e = t; e < 512; e += 256) {
            int row = e >> 3, kq = e & 7;
            float4 v = *(const float4*)&feat[(size_t)(m0 + row)*NFEAT + k0 + kq*4];
            ft[row*33 + kq*4 + 0] = v.x;
            ft[row*33 + kq*4 + 1] = v.y;
            ft[row*33 + kq*4 + 2] = v.z;
            ft[row*33 + kq*4 + 3] = v.w;
        }
        for (int e = t; e < 512; e += 256) {
            int kk = e >> 4, c4 = e & 15;
            float4 v = *(const float4*)&W[(size_t)(r0 + kk)*C_S + c0 + c4*4];
            *(float4*)&wt[kk*64 + c4*4] = v;
        }
        __syncthreads();

#pragma unroll 8
        for (int kk = 0; kk < 32; ++kk) {
            float4 w = *(const float4*)&wt[kk*64 + tc*4];
            float sv[4];
#pragma unroll
            for (int r = 0; r < 4; ++r) sv[r] = ft[(tm*4 + r)*33 + kk];
#pragma unroll
            for (int r = 0; r < 4; ++r) {
                acc[r][0] += sv[r] * w.x;
                acc[r][1] += sv[r] * w.y;
                acc[r][2] += sv[r] * w.z;
                acc[r][3] += sv[r] * w.w;
            }
        }
    }

#pragma unroll
    for (int r = 0; r < 4; ++r) {
        float4 o = make_float4(acc[r][0], acc[r][1], acc[r][2], acc[r][3]);
        *(float4*)&fout[((size_t)kc*N + m0 + tm*4 + r)*C_S + c0 + tc*4] = o;
    }
}

// ---------------------------------------------------------------------------
// Kernel 3d: reduce split-K partials + bias -> s_out. 768 blocks x 256.
// ---------------------------------------------------------------------------
__global__ __launch_bounds__(256) void k_red(
    const float* __restrict__ fout,
    const float* __restrict__ bhid, const float* __restrict__ bpair,
    const float* __restrict__ bpts, const float* __restrict__ bpn,
    float* __restrict__ s_out)
{
    const int idx = blockIdx.x * 256 + threadIdx.x;
    const int c = idx % C_S;
    float acc = bhid[c] + bpair[c] + bpts[c] + bpn[c];
#pragma unroll
    for (int kc = 0; kc < KSPLIT; ++kc)
        acc += fout[(size_t)kc*N*C_S + idx];
    s_out[idx] = acc;
}

extern "C" void kernel_launch(void* const* d_in, const int* in_sizes, int n_in,
                              void* d_out, int out_size, void* d_ws, size_t ws_size,
                              hipStream_t stream) {
    const float* s     = (const float*)d_in[0];
    const float* z     = (const float*)d_in[1];
    const float* rot   = (const float*)d_in[2];
    const float* trans = (const float*)d_in[3];
    const float* mask  = (const float*)d_in[4];
    const float* Wq    = (const float*)d_in[5];
    const float* bq    = (const float*)d_in[6];
    const float* Wkv   = (const float*)d_in[7];
    const float* bkv   = (const float*)d_in[8];
    const float* Wqp   = (const float*)d_in[9];
    const float* bqp   = (const float*)d_in[10];
    const float* Wkvp  = (const float*)d_in[11];
    const float* bkvp  = (const float*)d_in[12];
    const float* Wb    = (const float*)d_in[13];
    const float* bb    = (const float*)d_in[14];
    const float* hwts  = (const float*)d_in[15];
    const float* Whid  = (const float*)d_in[16];
    const float* bhid  = (const float*)d_in[17];
    const float* Wpair = (const float*)d_in[18];
    const float* bpair = (const float*)d_in[19];
    const float* Wpts  = (const float*)d_in[20];
    const float* bpts  = (const float*)d_in[21];
    const float* Wpn   = (const float*)d_in[22];
    const float* bpn   = (const float*)d_in[23];

    float* out   = (float*)d_out;
    float* s_out = out;                 // 512*384
    float* a_out = out + N*C_S;         // 12*512*512
    float* ws    = (float*)d_ws;

    k_gemm_proj<<<dim3(8, 18, PSPLIT), 256, 0, stream>>>(s, Wq, bq, Wkv, bkv,
                                                         Wqp, bqp, Wkvp, bkvp,
                                                         ws + WS_RAW);
    k_post<<<N, 256, 0, stream>>>(ws + WS_RAW, rot, trans, Wb, ws);
    k_logits<<<dim3(N, 8), 256, 0, stream>>>(ws, z, bb, hwts, mask, a_out);
    k_av<<<dim3(N, NJC), 256, 0, stream>>>(a_out, ws, z, ws);
    k_feat<<<N, 256, 0, stream>>>(rot, trans, ws);
    k_final_part<<<dim3(8, 6, KSPLIT), 256, 0, stream>>>(ws, Whid, Wpair, Wpts,
                                                         Wpn, ws + WS_FOUT);
    k_red<<<(N*C_S)/256, 256, 0, stream>>>(ws + WS_FOUT, bhid, bpair, bpts, bpn,
                                           s_out);
}